// Round 8
// baseline (2235.232 us; speedup 1.0000x reference)
//
#include <hip/hip_runtime.h>
#include <hip/hip_bf16.h>

typedef float   f32x4_t  __attribute__((ext_vector_type(4)));
typedef float   f32x2_t  __attribute__((ext_vector_type(2)));
typedef __bf16  bf16x8_t __attribute__((ext_vector_type(8)));
typedef int     i32x4_t  __attribute__((ext_vector_type(4)));

#define N_ROWS   16384
#define N_COLS   1000
#define N_COLS_P 1024
#define N_DIM    512
#define N_ITER   100
#define PBLK     256
#define PTHR     512
#define NRED     64        /* reducer blocks 0..63, 16 contiguous cols each */

// ---- control plane: relaxed agent-scope atomics (scalar, low-rate) ----
__device__ __forceinline__ int ldi_sc1(const int* p) {
    return __hip_atomic_load(p, __ATOMIC_RELAXED, __HIP_MEMORY_SCOPE_AGENT);
}
__device__ __forceinline__ void addi_sc1(int* p) {
    __hip_atomic_fetch_add(p, 1, __ATOMIC_RELAXED, __HIP_MEMORY_SCOPE_AGENT);
}
// ---- data plane: COALESCING coherent vector ops (sc0 sc1 = bypass L1+L2,
// read/write at L3-coherent point; normal TA inter-lane coalescing) ----
__device__ __forceinline__ f32x2_t ld2_coh(const float* p) {
    f32x2_t v;
    asm volatile("global_load_dwordx2 %0, %1, off sc0 sc1\n\t"
                 "s_waitcnt vmcnt(0)"
                 : "=&v"(v) : "v"(p) : "memory");
    return v;
}
__device__ __forceinline__ void ld4x2_coh(const float* pA, const float* pB,
                                          f32x4_t* a, f32x4_t* b) {
    asm volatile("global_load_dwordx4 %0, %2, off sc0 sc1\n\t"
                 "global_load_dwordx4 %1, %3, off sc0 sc1\n\t"
                 "s_waitcnt vmcnt(0)"
                 : "=&v"(*a), "=&v"(*b) : "v"(pA), "v"(pB) : "memory");
}
__device__ __forceinline__ void st2_coh(float* p, f32x2_t v) {
    asm volatile("global_store_dwordx2 %0, %1, off sc0 sc1"
                 :: "v"(p), "v"(v) : "memory");
}
__device__ __forceinline__ void st1_coh(float* p, float v) {
    asm volatile("global_store_dword %0, %1, off sc0 sc1"
                 :: "v"(p), "v"(v) : "memory");
}
__device__ __forceinline__ void drain_vmem() {
    asm volatile("s_waitcnt vmcnt(0)" ::: "memory");
}

__device__ __forceinline__ unsigned short f2bf(float f) {
    unsigned int u = __builtin_bit_cast(unsigned int, f);
    u += 0x7FFFu + ((u >> 16) & 1u);            // RNE round to bf16
    return (unsigned short)(u >> 16);
}

// ---------------------------------------------------------------------------
// GEMM pass: dot = F @ T^T ; K = exp(-2*s/(1-s)), s=2*dot.
// MODE 0: K as bf16 (stride 1024, zero-padded) into d_out + column partials.
// MODE 1: final plan out[i][j] = u[i]*K[i][j]*v[j] (f32, stride 1000).
// ---------------------------------------------------------------------------
template <int MODE>
__launch_bounds__(256)
__global__ void k_gemm(const float* __restrict__ F, const float* __restrict__ T,
                       void* __restrict__ Kout, float* __restrict__ cpart,
                       const float* __restrict__ v_com, const float* __restrict__ u_both,
                       const int* __restrict__ flags)
{
    __shared__ unsigned short lA[128 * 72];
    __shared__ unsigned short lB[128 * 72];
    __shared__ float cs_lds[4 * 64];

    const int bm = blockIdx.x;
    const int bn = blockIdx.y;
    const int m0 = bm << 7;
    const int n0 = bn << 7;
    const int t  = threadIdx.x;
    const int lane = t & 63;
    const int wid  = t >> 6;
    const int wr = wid >> 1;
    const int wc = wid & 1;

    f32x4_t acc[4][4];
#pragma unroll
    for (int a = 0; a < 4; ++a)
#pragma unroll
        for (int b = 0; b < 4; ++b)
            acc[a][b] = (f32x4_t){0.f, 0.f, 0.f, 0.f};

    const int srow = t >> 4;
    const int scol = (t & 15) << 2;

    for (int kt = 0; kt < N_DIM; kt += 64) {
#pragma unroll
        for (int r = 0; r < 8; ++r) {
            const int rr = srow + (r << 4);
            const float4 av = *(const float4*)(F + (size_t)(m0 + rr) * N_DIM + kt + scol);
            ushort4 a4; a4.x = f2bf(av.x); a4.y = f2bf(av.y); a4.z = f2bf(av.z); a4.w = f2bf(av.w);
            *(ushort4*)(&lA[rr * 72 + scol]) = a4;
            const int gn = n0 + rr;
            float4 bv = make_float4(0.f, 0.f, 0.f, 0.f);
            if (gn < N_COLS) bv = *(const float4*)(T + (size_t)gn * N_DIM + kt + scol);
            ushort4 b4; b4.x = f2bf(bv.x); b4.y = f2bf(bv.y); b4.z = f2bf(bv.z); b4.w = f2bf(bv.w);
            *(ushort4*)(&lB[rr * 72 + scol]) = b4;
        }
        __syncthreads();
#pragma unroll
        for (int ks = 0; ks < 2; ++ks) {
            bf16x8_t afr[4], bfr[4];
#pragma unroll
            for (int mf = 0; mf < 4; ++mf) {
                const int r = (wr << 6) + (mf << 4) + (lane & 15);
                const int off = r * 72 + (ks << 5) + ((lane >> 4) << 3);
                afr[mf] = __builtin_bit_cast(bf16x8_t, *(const i32x4_t*)(&lA[off]));
            }
#pragma unroll
            for (int nf = 0; nf < 4; ++nf) {
                const int r = (wc << 6) + (nf << 4) + (lane & 15);
                const int off = r * 72 + (ks << 5) + ((lane >> 4) << 3);
                bfr[nf] = __builtin_bit_cast(bf16x8_t, *(const i32x4_t*)(&lB[off]));
            }
#pragma unroll
            for (int mf = 0; mf < 4; ++mf)
#pragma unroll
                for (int nf = 0; nf < 4; ++nf)
                    acc[mf][nf] = __builtin_amdgcn_mfma_f32_16x16x32_bf16(
                        afr[mf], bfr[nf], acc[mf][nf], 0, 0, 0);
        }
        __syncthreads();
    }

    int usel = 2;
    if (MODE == 1) usel = flags[1];
    float csum[4] = {0.f, 0.f, 0.f, 0.f};
#pragma unroll
    for (int mf = 0; mf < 4; ++mf) {
#pragma unroll
        for (int nf = 0; nf < 4; ++nf) {
#pragma unroll
            for (int j = 0; j < 4; ++j) {
                const float d = acc[mf][nf][j];
                const float s = 2.f * d;
                const float M = s / (1.f - s);
                const float kv = __expf(-2.f * M);
                const int grow = m0 + (wr << 6) + (mf << 4) + ((lane >> 4) << 2) + j;
                const int gcol = n0 + (wc << 6) + (nf << 4) + (lane & 15);
                if (MODE == 0) {
                    ((unsigned short*)Kout)[(size_t)grow * N_COLS_P + gcol] =
                        (gcol < N_COLS) ? f2bf(kv) : (unsigned short)0;
                    csum[nf] += kv;
                } else {
                    if (gcol < N_COLS) {
                        const float u = (usel == 2) ? (1.f / 16384.f)
                                                    : u_both[(size_t)usel * N_ROWS + grow];
                        ((float*)Kout)[(size_t)grow * N_COLS + gcol] = u * kv * v_com[gcol];
                    }
                }
            }
        }
    }
    if (MODE == 0) {
#pragma unroll
        for (int nf = 0; nf < 4; ++nf) {
            csum[nf] += __shfl_xor(csum[nf], 16);
            csum[nf] += __shfl_xor(csum[nf], 32);
        }
        if (lane < 16) {
#pragma unroll
            for (int nf = 0; nf < 4; ++nf)
                cs_lds[wid * 64 + (nf << 4) + lane] = csum[nf];
        }
        __syncthreads();
        if (t < 128) {
            const int cw = t >> 6;
            const int c6 = t & 63;
            cpart[(size_t)bm * N_COLS_P + n0 + t] =
                cs_lds[cw * 64 + c6] + cs_lds[(cw + 2) * 64 + c6];
        }
    }
}

// ---------------------------------------------------------------------------
// init: ktu[0]=colsum(K)/16384 (u0=1/16384), pads=1; zero counters/flags.
// flags[1]=u_sel (2=uniform u0). pcnt/rcnt/flags2: [128] entries x 16-int pad.
// ---------------------------------------------------------------------------
__launch_bounds__(128)
__global__ void k_init(const float* __restrict__ cpart, float* __restrict__ ktu0,
                       float* __restrict__ vcom, int* __restrict__ flags,
                       int* __restrict__ pcnt, int* __restrict__ rcnt,
                       int* __restrict__ flags2)
{
    const int j = blockIdx.x * 128 + threadIdx.x;   // 0..1023
    if (j < N_COLS) {
        float s = 0.f;
        for (int p = 0; p < 128; ++p) s += cpart[(size_t)p * N_COLS_P + j];
        ktu0[j] = s * (1.f / 16384.f);
        vcom[j] = 1.f / 1000.f;
    } else {
        ktu0[j] = 1.f;                 // pad: b=0 -> v=0 (finite)
        vcom[j] = 0.f;
    }
    for (int z = j; z < 2048; z += 1024) { pcnt[z] = 0; rcnt[z] = 0; flags2[z] = 0; }
    if (j < 4) flags[j] = (j == 1) ? 2 : 0;
}

// ---------------------------------------------------------------------------
// Persistent Sinkhorn, counter protocol, COALESCED coherent data plane.
// 256 blocks x 512 thr, 1 block/CU. Thread t owns ktu/v columns {2t, 2t+1}.
// A) v=b/ktu (dwordx2 coherent) -> dots -> u -> partials (dwordx2 coherent);
//    drain; atomicAdd pcnt[ii].
// B) blocks<64: poll pcnt==256 (1 lane); read 256x16 partial tile as 2x
//    dwordx4/lane; fold; ktu_next (dword coherent); drain; atomicAdd rcnt[ii].
// top) poll rcnt[ii-1]==64 (1 lane); bad/commit/converged (uniform).
// ---------------------------------------------------------------------------
__launch_bounds__(PTHR, 2)
__global__ void k_persist(const unsigned short* __restrict__ Kb,
                          const float* __restrict__ ratios,
                          float* __restrict__ ktu,      // [2][1024]
                          float* __restrict__ utmp,     // [2][16384]
                          float* __restrict__ vcom,     // [1024]
                          float* __restrict__ partials, // [256][1024]
                          int* __restrict__ flags,
                          int* __restrict__ pcnt,       // [128*16]
                          int* __restrict__ rcnt,       // [128*16]
                          int* __restrict__ flags2)     // [128*16]
{
    __shared__ float vbuf[2][N_COLS_P];
    __shared__ float wp[8][N_COLS_P];
    __shared__ float redw[8][16];
    __shared__ float rbc;
    __shared__ int ibc;
    const int t = threadIdx.x, lane = t & 63, wid = t >> 6, b = blockIdx.x;
    const int row0 = (b << 6) + (wid << 3);
    const int c2 = t << 1;                  // this thread's two columns
    const bool isred = (b < NRED);

    // K preload: packed bf16 pairs, coalesced dword loads (plain/cached).
    unsigned kp[8][8];
#pragma unroll
    for (int r = 0; r < 8; ++r) {
        const unsigned* rp = (const unsigned*)(Kb + (size_t)(row0 + r) * N_COLS_P);
#pragma unroll
        for (int q = 0; q < 8; ++q) kp[r][q] = rp[(q << 6) + lane];
    }
    const float bj0 = (c2 < N_COLS) ? ratios[c2] * 16384.f : 0.f;
    const float bj1 = (c2 + 1 < N_COLS) ? ratios[c2 + 1] * 16384.f : 0.f;

    int usel = 2;

    for (int ii = 0; ii <= N_ITER; ++ii) {
        const int p = ii & 1;
        f32x2_t kc;

        if (ii > 0) {
            // ---- top: single-lane poll of reducer counter ----
            if (t == 0) {
                while (ldi_sc1(&rcnt[(ii - 1) << 4]) < NRED)
                    __builtin_amdgcn_s_sleep(1);
                ibc = ldi_sc1(&flags2[(ii - 1) << 4]);
            }
            __syncthreads();
            if (ibc) break;               // bad(ii-1): revert to parity(ii-2)
            usel = (ii - 1) & 1;          // commit iter ii-1
            kc = ld2_coh(&ktu[(p << 10) + c2]);
            if (((ii - 1) % 10) == 0) {   // convergence check of iter ii-1
                const float vo0 = vbuf[usel][c2], vo1 = vbuf[usel][c2 + 1];
                const float d0 = (c2 < N_COLS) ? kc[0] * vo0 - bj0 : 0.f;
                const float d1 = (c2 + 1 < N_COLS) ? kc[1] * vo1 - bj1 : 0.f;
                float e = d0 * d0 + d1 * d1;
#pragma unroll
                for (int sh = 1; sh <= 32; sh <<= 1) e += __shfl_xor(e, sh);
                if (lane == 0) redw[wid][0] = e;
                __syncthreads();
                if (t == 0) {
                    float s = 0.f;
#pragma unroll
                    for (int w = 0; w < 8; ++w) s += redw[w][0];
                    rbc = s;
                }
                __syncthreads();
                if (rbc < 1e-18f) break;  // converged at ii-1 (committed)
            }
            if (ii == N_ITER) break;      // epilogue-only pass
        } else {
            kc = ld2_coh(&ktu[c2]);
        }

        // ---- phase A: vnew (uniform badv check) ----
        const float v0 = bj0 / kc[0];
        const float v1 = bj1 / kc[1];
        const int badv = (kc[0] == 0.f) | (kc[1] == 0.f) |
                         (!isfinite(v0)) | (!isfinite(v1));
        *(f32x2_t*)&vbuf[p][c2] = (f32x2_t){v0, v1};
        if (__syncthreads_or(badv)) break;   // uniform: revert to parity(ii-1)

        float vr[16];
#pragma unroll
        for (int q = 0; q < 8; ++q) {
            const f32x2_t vv = *(const f32x2_t*)&vbuf[p][(q << 7) + (lane << 1)];
            vr[2*q] = vv[0]; vr[2*q+1] = vv[1];
        }
        float dots[8];
#pragma unroll
        for (int r = 0; r < 8; ++r) {
            float p0 = 0.f, p1 = 0.f, p2 = 0.f, p3 = 0.f;
#pragma unroll
            for (int q = 0; q < 8; ++q) {
                const unsigned u = kp[r][q];
                const float lo = __builtin_bit_cast(float, u << 16);
                const float hi = __builtin_bit_cast(float, u & 0xFFFF0000u);
                if (q & 1) { p2 = fmaf(lo, vr[2*q], p2); p3 = fmaf(hi, vr[2*q+1], p3); }
                else       { p0 = fmaf(lo, vr[2*q], p0); p1 = fmaf(hi, vr[2*q+1], p1); }
            }
            dots[r] = (p0 + p1) + (p2 + p3);
        }
#pragma unroll
        for (int s = 1; s <= 32; s <<= 1) {
#pragma unroll
            for (int r = 0; r < 8; ++r) dots[r] += __shfl_xor(dots[r], s);
        }
        float u8[8];
        int ubad = 0;
#pragma unroll
        for (int r = 0; r < 8; ++r) { u8[r] = 1.f / dots[r]; ubad |= !isfinite(u8[r]); }
        if (lane == 0) {
            float* uo = utmp + ((size_t)p << 14) + row0;
#pragma unroll
            for (int r = 0; r < 8; ++r) uo[r] = u8[r];
        }
        if (__any(ubad) && lane == 0)
            __hip_atomic_fetch_or(&flags2[ii << 4], 1, __ATOMIC_RELAXED,
                                  __HIP_MEMORY_SCOPE_AGENT);

        float creg[16];
#pragma unroll
        for (int e = 0; e < 16; ++e) creg[e] = 0.f;
#pragma unroll
        for (int r = 0; r < 8; ++r) {
#pragma unroll
            for (int q = 0; q < 8; ++q) {
                const unsigned u = kp[r][q];
                const float lo = __builtin_bit_cast(float, u << 16);
                const float hi = __builtin_bit_cast(float, u & 0xFFFF0000u);
                creg[2*q]   = fmaf(lo, u8[r], creg[2*q]);
                creg[2*q+1] = fmaf(hi, u8[r], creg[2*q+1]);
            }
        }
#pragma unroll
        for (int q = 0; q < 8; ++q)
            *(f32x2_t*)&wp[wid][(q << 7) + (lane << 1)] = (f32x2_t){creg[2*q], creg[2*q+1]};
        __syncthreads();
        {
            const int j2 = t << 1;
            f32x2_t s2 = *(const f32x2_t*)&wp[0][j2];
#pragma unroll
            for (int w = 1; w < 8; ++w) {
                const f32x2_t x = *(const f32x2_t*)&wp[w][j2];
                s2[0] += x[0]; s2[1] += x[1];
            }
            st2_coh(&partials[((size_t)b << 10) + j2], s2);
        }
        drain_vmem();                     // partial stores + flags2 at L3
        __syncthreads();
        if (t == 0) addi_sc1(&pcnt[ii << 4]);

        // ---- phase B: reducers ----
        if (isred) {
            if (t == 0) {
                while (ldi_sc1(&pcnt[ii << 4]) < PBLK)
                    __builtin_amdgcn_s_sleep(1);
            }
            __syncthreads();
            // lane layout: 16 row-groups x 4 col-quads; 2 row-blocks of 128
            const int cbase = (b << 4) + ((lane & 3) << 2);
            const int rowA  = (wid << 4) + (lane >> 2);
            f32x4_t a, bq;
            ld4x2_coh(&partials[((size_t)rowA << 10) + cbase],
                      &partials[((size_t)(rowA + 128) << 10) + cbase], &a, &bq);
            f32x4_t s4;
#pragma unroll
            for (int e = 0; e < 4; ++e) s4[e] = a[e] + bq[e];
#pragma unroll
            for (int sh = 4; sh <= 32; sh <<= 1) {
#pragma unroll
                for (int e = 0; e < 4; ++e) s4[e] += __shfl_xor(s4[e], sh);
            }
            if (lane < 4) *(f32x4_t*)&redw[wid][lane << 2] = s4;
            __syncthreads();
            if (t < 16) {
                float s2 = 0.f;
#pragma unroll
                for (int w = 0; w < 8; ++w) s2 += redw[w][t];
                const int c = (b << 4) + t;
                st1_coh(&ktu[(((ii + 1) & 1) << 10) + c], (c < N_COLS) ? s2 : 1.f);
            }
            drain_vmem();
            __syncthreads();
            if (t == 0) addi_sc1(&rcnt[ii << 4]);
        }
    }

    // ---- epilogue: block 0 materializes committed v and u_sel ----
    if (b == 0) {
        if (c2 < N_COLS)
            vcom[c2] = (usel == 2) ? (1.f / 1000.f) : vbuf[usel][c2];
        if (c2 + 1 < N_COLS)
            vcom[c2 + 1] = (usel == 2) ? (1.f / 1000.f) : vbuf[usel][c2 + 1];
        if (t == 0) flags[1] = usel;
    }
}

extern "C" void kernel_launch(void* const* d_in, const int* in_sizes, int n_in,
                              void* d_out, int out_size, void* d_ws, size_t ws_size,
                              hipStream_t stream)
{
    const float* F      = (const float*)d_in[0];
    const float* T      = (const float*)d_in[1];
    const float* ratios = (const float*)d_in[2];
    float* out = (float*)d_out;
    unsigned short* Kb = (unsigned short*)d_out;   // bf16 K, stride 1024

    float* ws        = (float*)d_ws;
    float* partials  = ws;                                   // 256*1024
    float* ktu       = partials + (size_t)PBLK * N_COLS_P;   // 2*1024
    float* utmp      = ktu + 2 * N_COLS_P;                   // 2*16384
    float* vcom      = utmp + 2 * N_ROWS;                    // 1024
    int*   flags     = (int*)(vcom + N_COLS_P);              // 16 (padded)
    int*   pcnt      = flags + 16;                           // 128*16
    int*   rcnt      = pcnt + 2048;                          // 128*16
    int*   flags2    = rcnt + 2048;                          // 128*16
    const size_t need_bytes = ((size_t)PBLK * N_COLS_P + 2 * N_COLS_P + 2 * N_ROWS +
                               N_COLS_P) * sizeof(float) +
                              (16 + 3 * 2048) * sizeof(int);
    if (ws_size < need_bytes) return;

    k_gemm<0><<<dim3(128, 8), 256, 0, stream>>>(F, T, Kb, partials, nullptr, nullptr, flags);
    k_init<<<8, 128, 0, stream>>>(partials, ktu, vcom, flags, pcnt, rcnt, flags2);
    k_persist<<<PBLK, PTHR, 0, stream>>>(Kb, ratios, ktu, utmp, vcom, partials,
                                         flags, pcnt, rcnt, flags2);
    k_gemm<1><<<dim3(128, 8), 256, 0, stream>>>(F, T, out, nullptr, vcom, utmp, flags);
}